// Round 6
// baseline (1267.175 us; speedup 1.0000x reference)
//
#include <hip/hip_runtime.h>
#include <math.h>

#define N_NODES 50000
#define N_EDGES 800000
#define NFEAT   512
#define HID     96
#define NCLASS  64
#define NUM_LAYERS 8
#define ALPHA   0.1f
#define NSB     49          // scan blocks: ceil(50000/1024)

typedef __attribute__((ext_vector_type(8))) short short8;
typedef __attribute__((ext_vector_type(4))) float f32x4;

__device__ __forceinline__ unsigned short f2bf(float f) {
    unsigned int u = __float_as_uint(f);
    unsigned int r = u + 0x7FFF + ((u >> 16) & 1);   // round-to-nearest-even
    return (unsigned short)(r >> 16);
}
__device__ __forceinline__ float bflo(unsigned int u) { return __uint_as_float(u << 16); }
__device__ __forceinline__ float bfhi(unsigned int u) { return __uint_as_float(u & 0xFFFF0000u); }

// ---------------- CSR build (rows padded to multiple of 4, dummy = N_NODES) ----------------
__global__ void hist_kernel(const int* __restrict__ dst, int* __restrict__ deg) {
    int e = blockIdx.x * blockDim.x + threadIdx.x;
    if (e < N_EDGES) atomicAdd(&deg[dst[e]], 1);
}

__global__ void scan1_kernel(const int* __restrict__ deg, int* __restrict__ row_start,
                             int* __restrict__ blk_sum) {
    __shared__ int sd[1024];
    int t = threadIdx.x;
    int i = blockIdx.x * 1024 + t;
    int v = (i < N_NODES) ? ((deg[i] + 3) & ~3) : 0;   // padded degree
    sd[t] = v;
    __syncthreads();
    for (int off = 1; off < 1024; off <<= 1) {
        int tv = (t >= off) ? sd[t - off] : 0;
        __syncthreads();
        sd[t] += tv;
        __syncthreads();
    }
    if (i < N_NODES) row_start[i] = sd[t] - v;          // exclusive, block-local
    if (t == 1023) blk_sum[blockIdx.x] = sd[1023];
}

__global__ void scan2_kernel(const int* __restrict__ blk_sum, int* __restrict__ blk_off) {
    if (threadIdx.x == 0) {
        int acc = 0;
        for (int b = 0; b < NSB; b++) { blk_off[b] = acc; acc += blk_sum[b]; }
    }
}

__global__ void scan3_kernel(int* __restrict__ row_start, const int* __restrict__ blk_off) {
    int i = blockIdx.x * 1024 + threadIdx.x;
    if (i < N_NODES) row_start[i] += blk_off[blockIdx.x];
}

__global__ void fill_kernel(const int* __restrict__ src, const int* __restrict__ dst,
                            const int* __restrict__ row_start, int* __restrict__ cursor,
                            int* __restrict__ csr_src) {
    int e = blockIdx.x * blockDim.x + threadIdx.x;
    if (e < N_EDGES) {
        int d = dst[e];
        int pos = row_start[d] + atomicAdd(&cursor[d], 1);
        csr_src[pos] = src[e];
    }
}

__global__ void pad_kernel(const int* __restrict__ deg, const int* __restrict__ row_start,
                           int* __restrict__ csr_src) {
    int n = blockIdx.x * blockDim.x + threadIdx.x;
    if (n < N_NODES) {
        int d = deg[n], pd = (d + 3) & ~3, rs = row_start[n];
        for (int p = d; p < pd; p++) csr_src[rs + p] = N_NODES;  // dummy zero row
    }
}

// ---------------- degree-bucket permutation (kills gather-wave divergence) ----------------
__global__ void bin_hist_kernel(const int* __restrict__ deg, int* __restrict__ bin_cnt) {
    int n = blockIdx.x * blockDim.x + threadIdx.x;
    if (n < N_NODES) {
        int nq = (deg[n] + 3) >> 2; if (nq > 63) nq = 63;
        atomicAdd(&bin_cnt[nq], 1);
    }
}
__global__ void bin_scan_kernel(const int* __restrict__ bin_cnt, int* __restrict__ bin_off) {
    if (threadIdx.x == 0) {
        int acc = 0;
        for (int b = 63; b >= 0; b--) { bin_off[b] = acc; acc += bin_cnt[b]; }  // descending nq
    }
}
__global__ void bin_fill_kernel(const int* __restrict__ deg, const int* __restrict__ bin_off,
                                int* __restrict__ bin_cur, int* __restrict__ perm) {
    int n = blockIdx.x * blockDim.x + threadIdx.x;
    if (n < N_NODES) {
        int nq = (deg[n] + 3) >> 2; if (nq > 63) nq = 63;
        int pos = bin_off[nq] + atomicAdd(&bin_cur[nq], 1);
        perm[pos] = n;
    }
}

__global__ void zero_dummy_kernel(short* __restrict__ ha, short* __restrict__ hb) {
    int t = threadIdx.x;
    if (t < HID) {
        ha[(size_t)N_NODES * HID + t] = 0;
        hb[(size_t)N_NODES * HID + t] = 0;
    }
}

// ---------------- weight converts: col-major bf16 for MFMA B operands ----------------
__global__ void convert_win_kernel(const float* __restrict__ W, short* __restrict__ Wt) {
    int n = blockIdx.x;    // 0..95
    int k = threadIdx.x;   // 0..511
    Wt[(size_t)n * NFEAT + k] = (short)f2bf(W[(size_t)k * HID + n]);
}

__global__ void convert_wout_kernel(const float* __restrict__ W, short* __restrict__ Wt) {
    int n = blockIdx.x;    // 0..63
    int k = threadIdx.x;   // 0..95
    Wt[(size_t)n * HID + k] = (short)f2bf(W[(size_t)k * NCLASS + n]);
}

// ---------------- input GEMM via MFMA bf16, LDS-free / barrier-free ----------------
// Wave owns 16 rows exclusively -> each lane loads its own A fragment from global
// (quads split each 128-B cache line of x), converts in-register, no __syncthreads.
__global__ __launch_bounds__(256) void gemm_in_kernel(
        const float* __restrict__ x, const short* __restrict__ Wt,
        const float* __restrict__ b, short* __restrict__ h_bf, float* __restrict__ x0) {
    int tid  = threadIdx.x;
    int wave = tid >> 6, lane = tid & 63;
    int quad = lane >> 4, l16 = lane & 15;
    int row0 = blockIdx.x * 64 + wave * 16;   // wave's 16-row tile
    int arow = row0 + l16; if (arow >= N_NODES) arow = N_NODES - 1;
    const float* xrow = &x[(size_t)arow * NFEAT];

    f32x4 acc[6];
#pragma unroll
    for (int n = 0; n < 6; n++) acc[n] = (f32x4){0.f, 0.f, 0.f, 0.f};

#pragma unroll 4
    for (int k0 = 0; k0 < NFEAT; k0 += 32) {
        float4 v0 = *(const float4*)&xrow[k0 + quad * 8];
        float4 v1 = *(const float4*)&xrow[k0 + quad * 8 + 4];
        union { short8 s; uint4 u; } af;
        af.u.x = (unsigned)f2bf(v0.x) | ((unsigned)f2bf(v0.y) << 16);
        af.u.y = (unsigned)f2bf(v0.z) | ((unsigned)f2bf(v0.w) << 16);
        af.u.z = (unsigned)f2bf(v1.x) | ((unsigned)f2bf(v1.y) << 16);
        af.u.w = (unsigned)f2bf(v1.z) | ((unsigned)f2bf(v1.w) << 16);
#pragma unroll
        for (int n = 0; n < 6; n++) {
            short8 bfrag = *(const short8*)&Wt[(size_t)(n * 16 + l16) * NFEAT + k0 + quad * 8];
            acc[n] = __builtin_amdgcn_mfma_f32_16x16x32_bf16(af.s, bfrag, acc[n], 0, 0, 0);
        }
    }
#pragma unroll
    for (int n = 0; n < 6; n++) {
        int col = n * 16 + l16;
        float bias = b[col];
#pragma unroll
        for (int r = 0; r < 4; r++) {
            int grow = row0 + quad * 4 + r;
            if (grow < N_NODES) {
                float v = acc[n][r] + bias;
                v = v > 0.f ? v : 0.f;
                h_bf[(size_t)grow * HID + col] = (short)f2bf(v);
                x0[(size_t)grow * HID + col]   = v;
            }
        }
    }
}

// ---------------- fused layer: bf16 gather + residual mix + fp32 96x96 GEMM + relu -> bf16 --
// block (12,32): ty = node slot (degree-sorted via perm), tx = 8-feature chunk. 16B gathers.
__global__ __launch_bounds__(384) void layer_kernel(
        const short* __restrict__ h_in, const float* __restrict__ x0,
        const int* __restrict__ row_start, const int* __restrict__ deg,
        const int* __restrict__ csr_src, const int* __restrict__ perm,
        const float* __restrict__ W, float beta, short* __restrict__ h_out) {
    __shared__ float Ws[96][100];   // fp32 weights, padded
    __shared__ float As[32][100];   // hc fp32, padded
    int tx = threadIdx.x;           // 0..11
    int ty = threadIdx.y;           // 0..31
    int tid = ty * 12 + tx;
    int idx = blockIdx.x * 32 + ty;
    bool valid = idx < N_NODES;
    int node = valid ? perm[idx] : (N_NODES - 1);

    // stage W (fp32) into LDS; in flight during gather
#pragma unroll
    for (int j = 0; j < 6; j++) {
        int s = tid + j * 384;                  // float4 index, 2304 total
        int r = s / 24, cq = s % 24;
        *(float4*)&Ws[r][cq * 4] = ((const float4*)W)[s];
    }

    int s = row_start[node];
    int d = deg[node];
    int nq = (d + 3) >> 2;
    const int4* c4 = (const int4*)(csr_src + s);
    float acc[8];
#pragma unroll
    for (int j = 0; j < 8; j++) acc[j] = 0.f;
    for (int i = 0; i < nq; i++) {
        int4 idxv = c4[i];
        uint4 a0 = *(const uint4*)&h_in[(size_t)idxv.x * HID + tx * 8];
        uint4 a1 = *(const uint4*)&h_in[(size_t)idxv.y * HID + tx * 8];
        uint4 a2 = *(const uint4*)&h_in[(size_t)idxv.z * HID + tx * 8];
        uint4 a3 = *(const uint4*)&h_in[(size_t)idxv.w * HID + tx * 8];
        acc[0] += bflo(a0.x) + bflo(a1.x) + bflo(a2.x) + bflo(a3.x);
        acc[1] += bfhi(a0.x) + bfhi(a1.x) + bfhi(a2.x) + bfhi(a3.x);
        acc[2] += bflo(a0.y) + bflo(a1.y) + bflo(a2.y) + bflo(a3.y);
        acc[3] += bfhi(a0.y) + bfhi(a1.y) + bfhi(a2.y) + bfhi(a3.y);
        acc[4] += bflo(a0.z) + bflo(a1.z) + bflo(a2.z) + bflo(a3.z);
        acc[5] += bfhi(a0.z) + bfhi(a1.z) + bfhi(a2.z) + bfhi(a3.z);
        acc[6] += bflo(a0.w) + bflo(a1.w) + bflo(a2.w) + bflo(a3.w);
        acc[7] += bfhi(a0.w) + bfhi(a1.w) + bfhi(a2.w) + bfhi(a3.w);
    }
    float4 r0 = *(const float4*)&x0[(size_t)node * HID + tx * 8];
    float4 r1 = *(const float4*)&x0[(size_t)node * HID + tx * 8 + 4];
    float hc[8];
    hc[0] = (1.f - ALPHA) * acc[0] + ALPHA * r0.x;
    hc[1] = (1.f - ALPHA) * acc[1] + ALPHA * r0.y;
    hc[2] = (1.f - ALPHA) * acc[2] + ALPHA * r0.z;
    hc[3] = (1.f - ALPHA) * acc[3] + ALPHA * r0.w;
    hc[4] = (1.f - ALPHA) * acc[4] + ALPHA * r1.x;
    hc[5] = (1.f - ALPHA) * acc[5] + ALPHA * r1.y;
    hc[6] = (1.f - ALPHA) * acc[6] + ALPHA * r1.z;
    hc[7] = (1.f - ALPHA) * acc[7] + ALPHA * r1.w;
    *(float4*)&As[ty][tx * 8]     = *(float4*)&hc[0];
    *(float4*)&As[ty][tx * 8 + 4] = *(float4*)&hc[4];
    __syncthreads();

    // GEMM: cols c0..c0+7 per thread, fp32
    int c0 = tx * 8;
    float g[8];
#pragma unroll
    for (int j = 0; j < 8; j++) g[j] = 0.f;
#pragma unroll 4
    for (int k = 0; k < 96; k++) {
        float a = As[ty][k];
        float4 w0 = *(const float4*)&Ws[k][c0];
        float4 w1 = *(const float4*)&Ws[k][c0 + 4];
        g[0] += a * w0.x; g[1] += a * w0.y; g[2] += a * w0.z; g[3] += a * w0.w;
        g[4] += a * w1.x; g[5] += a * w1.y; g[6] += a * w1.z; g[7] += a * w1.w;
    }
    if (valid) {
        float ob = 1.0f - beta;
        unsigned int pk[4];
#pragma unroll
        for (int j = 0; j < 4; j++) {
            float v0 = ob * hc[2*j]   + beta * g[2*j];
            float v1 = ob * hc[2*j+1] + beta * g[2*j+1];
            v0 = v0 > 0.f ? v0 : 0.f;
            v1 = v1 > 0.f ? v1 : 0.f;
            pk[j] = (unsigned)f2bf(v0) | ((unsigned)f2bf(v1) << 16);
        }
        *(uint4*)&h_out[(size_t)node * HID + c0] = *(uint4*)pk;
    }
}

// ---------------- output GEMM (MFMA bf16) + fused log_softmax ----------------
__global__ __launch_bounds__(256) void out_kernel(
        const short* __restrict__ h_bf, const short* __restrict__ Wt,
        const float* __restrict__ b, float* __restrict__ out) {
    int tid = threadIdx.x;
    int wave = tid >> 6, lane = tid & 63;
    int quad = lane >> 4, l16 = lane & 15;
    int row0 = blockIdx.x * 64 + wave * 16;

    f32x4 acc[4];
#pragma unroll
    for (int n = 0; n < 4; n++) acc[n] = (f32x4){0.f, 0.f, 0.f, 0.f};

    int arow = row0 + l16; if (arow > N_NODES) arow = N_NODES;  // dummy row is zero
#pragma unroll
    for (int ks = 0; ks < 3; ks++) {
        short8 afrag = *(const short8*)&h_bf[(size_t)arow * HID + ks * 32 + quad * 8];
#pragma unroll
        for (int n = 0; n < 4; n++) {
            short8 bfrag = *(const short8*)&Wt[(size_t)(n * 16 + l16) * HID + ks * 32 + quad * 8];
            acc[n] = __builtin_amdgcn_mfma_f32_16x16x32_bf16(afrag, bfrag, acc[n], 0, 0, 0);
        }
    }
#pragma unroll
    for (int n = 0; n < 4; n++) {
        float bias = b[n * 16 + l16];
#pragma unroll
        for (int r = 0; r < 4; r++) acc[n][r] += bias;
    }
#pragma unroll
    for (int r = 0; r < 4; r++) {
        float m = acc[0][r];
        m = fmaxf(m, acc[1][r]); m = fmaxf(m, acc[2][r]); m = fmaxf(m, acc[3][r]);
#pragma unroll
        for (int off = 1; off < 16; off <<= 1) m = fmaxf(m, __shfl_xor(m, off));
        float s = __expf(acc[0][r] - m) + __expf(acc[1][r] - m)
                + __expf(acc[2][r] - m) + __expf(acc[3][r] - m);
#pragma unroll
        for (int off = 1; off < 16; off <<= 1) s += __shfl_xor(s, off);
        float lse = m + __logf(s);
        int grow = row0 + quad * 4 + r;
        if (grow < N_NODES) {
#pragma unroll
            for (int n = 0; n < 4; n++)
                out[(size_t)grow * NCLASS + n * 16 + l16] = acc[n][r] - lse;
        }
    }
}

extern "C" void kernel_launch(void* const* d_in, const int* in_sizes, int n_in,
                              void* d_out, int out_size, void* d_ws, size_t ws_size,
                              hipStream_t stream) {
    const float* x      = (const float*)d_in[0];
    const int*   ei     = (const int*)d_in[1];
    const int*   srcp   = ei;
    const int*   dstp   = ei + N_EDGES;
    const float* W_in   = (const float*)d_in[2];
    const float* b_in   = (const float*)d_in[3];
    const float* conv_W = (const float*)d_in[4];
    const float* W_out  = (const float*)d_in[5];
    const float* b_out  = (const float*)d_in[6];
    float* out = (float*)d_out;

    short* h_a = (short*)d_ws;                               // (N+1) x HID bf16
    short* h_b = h_a + (size_t)(N_NODES + 1) * HID;
    float* x0  = (float*)(h_b + (size_t)(N_NODES + 1) * HID);
    short* Wt_in  = (short*)(x0 + (size_t)N_NODES * HID);    // 96 x 512
    short* Wt_out = Wt_in + (size_t)HID * NFEAT;             // 64 x 96
    int* deg       = (int*)(Wt_out + (size_t)NCLASS * HID);
    int* row_start = deg + N_NODES;
    int* cursor    = row_start + N_NODES;
    int* blk_sum   = cursor + N_NODES;
    int* blk_off   = blk_sum + 64;
    int* bin_cnt   = blk_off + 64;
    int* bin_off   = bin_cnt + 64;
    int* bin_cur   = bin_off + 64;
    int* perm      = bin_cur + 64;
    int* csr_src   = perm + N_NODES;                         // <= N_EDGES + 3*N_NODES ints

    hipMemsetAsync(deg,     0, N_NODES * sizeof(int), stream);
    hipMemsetAsync(cursor,  0, N_NODES * sizeof(int), stream);
    hipMemsetAsync(bin_cnt, 0, 128 * sizeof(int), stream);   // bin_cnt + bin_off slot reuse ok
    hipMemsetAsync(bin_cur, 0, 64 * sizeof(int), stream);
    hist_kernel<<<(N_EDGES + 255) / 256, 256, 0, stream>>>(dstp, deg);
    scan1_kernel<<<NSB, 1024, 0, stream>>>(deg, row_start, blk_sum);
    scan2_kernel<<<1, 64, 0, stream>>>(blk_sum, blk_off);
    scan3_kernel<<<NSB, 1024, 0, stream>>>(row_start, blk_off);
    fill_kernel<<<(N_EDGES + 255) / 256, 256, 0, stream>>>(srcp, dstp, row_start, cursor, csr_src);
    pad_kernel<<<(N_NODES + 255) / 256, 256, 0, stream>>>(deg, row_start, csr_src);
    bin_hist_kernel<<<(N_NODES + 255) / 256, 256, 0, stream>>>(deg, bin_cnt);
    bin_scan_kernel<<<1, 64, 0, stream>>>(bin_cnt, bin_off);
    bin_fill_kernel<<<(N_NODES + 255) / 256, 256, 0, stream>>>(deg, bin_off, bin_cur, perm);

    convert_win_kernel<<<HID, NFEAT, 0, stream>>>(W_in, Wt_in);
    convert_wout_kernel<<<NCLASS, HID, 0, stream>>>(W_out, Wt_out);
    gemm_in_kernel<<<(N_NODES + 63) / 64, 256, 0, stream>>>(x, Wt_in, b_in, h_a, x0);
    zero_dummy_kernel<<<1, 128, 0, stream>>>(h_a, h_b);

    short* cur = h_a;
    short* nxt = h_b;
    for (int l = 0; l < NUM_LAYERS; l++) {
        float beta = logf(0.5f / (float)(l + 1) + 1.0f);
        layer_kernel<<<(N_NODES + 31) / 32, dim3(12, 32), 0, stream>>>(
            cur, x0, row_start, deg, csr_src, perm, conv_W + (size_t)l * HID * HID, beta, nxt);
        short* t = cur; cur = nxt; nxt = t;
    }

    out_kernel<<<(N_NODES + 63) / 64, 256, 0, stream>>>(cur, Wt_out, b_out, out);
}

// Round 7
// 688.277 us; speedup vs baseline: 1.8411x; 1.8411x over previous
//
#include <hip/hip_runtime.h>
#include <math.h>

#define N_NODES 50000
#define N_EDGES 800000
#define NFEAT   512
#define HID     96
#define NCLASS  64
#define NUM_LAYERS 8
#define ALPHA   0.1f
#define NSB     49          // scan blocks: ceil(50000/1024)
#define NBB     196         // bin blocks: ceil(50000/256)

typedef __attribute__((ext_vector_type(8))) short short8;
typedef __attribute__((ext_vector_type(4))) float f32x4;

__device__ __forceinline__ unsigned short f2bf(float f) {
    unsigned int u = __float_as_uint(f);
    unsigned int r = u + 0x7FFF + ((u >> 16) & 1);   // round-to-nearest-even
    return (unsigned short)(r >> 16);
}
__device__ __forceinline__ float bflo(unsigned int u) { return __uint_as_float(u << 16); }
__device__ __forceinline__ float bfhi(unsigned int u) { return __uint_as_float(u & 0xFFFF0000u); }

// ---------------- CSR build (rows padded to multiple of 4, dummy = N_NODES) ----------------
__global__ void hist_kernel(const int* __restrict__ dst, int* __restrict__ deg) {
    int e = blockIdx.x * blockDim.x + threadIdx.x;
    if (e < N_EDGES) atomicAdd(&deg[dst[e]], 1);
}

__global__ void scan1_kernel(const int* __restrict__ deg, int* __restrict__ row_start,
                             int* __restrict__ blk_sum) {
    __shared__ int sd[1024];
    int t = threadIdx.x;
    int i = blockIdx.x * 1024 + t;
    int v = (i < N_NODES) ? ((deg[i] + 3) & ~3) : 0;   // padded degree
    sd[t] = v;
    __syncthreads();
    for (int off = 1; off < 1024; off <<= 1) {
        int tv = (t >= off) ? sd[t - off] : 0;
        __syncthreads();
        sd[t] += tv;
        __syncthreads();
    }
    if (i < N_NODES) row_start[i] = sd[t] - v;          // exclusive, block-local
    if (t == 1023) blk_sum[blockIdx.x] = sd[1023];
}

__global__ void scan2_kernel(const int* __restrict__ blk_sum, int* __restrict__ blk_off) {
    if (threadIdx.x == 0) {
        int acc = 0;
        for (int b = 0; b < NSB; b++) { blk_off[b] = acc; acc += blk_sum[b]; }
    }
}

__global__ void scan3_kernel(int* __restrict__ row_start, const int* __restrict__ blk_off) {
    int i = blockIdx.x * 1024 + threadIdx.x;
    if (i < N_NODES) row_start[i] += blk_off[blockIdx.x];
}

__global__ void fill_kernel(const int* __restrict__ src, const int* __restrict__ dst,
                            const int* __restrict__ row_start, int* __restrict__ cursor,
                            int* __restrict__ csr_src) {
    int e = blockIdx.x * blockDim.x + threadIdx.x;
    if (e < N_EDGES) {
        int d = dst[e];
        int pos = row_start[d] + atomicAdd(&cursor[d], 1);
        csr_src[pos] = src[e];
    }
}

__global__ void pad_kernel(const int* __restrict__ deg, const int* __restrict__ row_start,
                           int* __restrict__ csr_src) {
    int n = blockIdx.x * blockDim.x + threadIdx.x;
    if (n < N_NODES) {
        int d = deg[n], pd = (d + 3) & ~3, rs = row_start[n];
        for (int p = d; p < pd; p++) csr_src[rs + p] = N_NODES;  // dummy zero row
    }
}

// -------- degree-bucket permutation, contention-free counting sort (3 passes) --------
// Pass 1: per-block LDS histogram -> block-local rank per node + per-block bin counts.
__global__ __launch_bounds__(256) void bin_hist2_kernel(
        const int* __restrict__ deg, int* __restrict__ node_rank,
        int* __restrict__ blk_bin_cnt) {
    __shared__ int lh[64];
    int t = threadIdx.x;
    if (t < 64) lh[t] = 0;
    __syncthreads();
    int n = blockIdx.x * 256 + t;
    if (n < N_NODES) {
        int nq = (deg[n] + 3) >> 2; if (nq > 63) nq = 63;
        node_rank[n] = atomicAdd(&lh[nq], 1);      // LDS atomic: block-private
    }
    __syncthreads();
    if (t < 64) blk_bin_cnt[blockIdx.x * 64 + t] = lh[t];
}

// Pass 2: thread b owns bin b; serial scan over blocks -> per-block offsets; then
// descending-bin global bases (big degrees first).
__global__ void bin_offsets_kernel(const int* __restrict__ blk_bin_cnt,
                                   int* __restrict__ blk_bin_off,
                                   int* __restrict__ bin_base) {
    __shared__ int tot[64];
    int b = threadIdx.x;  // 0..63
    int acc = 0;
    for (int blk = 0; blk < NBB; blk++) {
        blk_bin_off[blk * 64 + b] = acc;
        acc += blk_bin_cnt[blk * 64 + b];
    }
    tot[b] = acc;
    __syncthreads();
    if (b == 0) {
        int a = 0;
        for (int i = 63; i >= 0; i--) { bin_base[i] = a; a += tot[i]; }
    }
}

// Pass 3: scatter, no atomics.
__global__ __launch_bounds__(256) void bin_place_kernel(
        const int* __restrict__ deg, const int* __restrict__ node_rank,
        const int* __restrict__ blk_bin_off, const int* __restrict__ bin_base,
        int* __restrict__ perm) {
    int n = blockIdx.x * 256 + threadIdx.x;
    if (n < N_NODES) {
        int nq = (deg[n] + 3) >> 2; if (nq > 63) nq = 63;
        perm[bin_base[nq] + blk_bin_off[blockIdx.x * 64 + nq] + node_rank[n]] = n;
    }
}

__global__ void zero_dummy_kernel(short* __restrict__ ha, short* __restrict__ hb) {
    int t = threadIdx.x;
    if (t < HID) {
        ha[(size_t)N_NODES * HID + t] = 0;
        hb[(size_t)N_NODES * HID + t] = 0;
    }
}

// ---------------- weight converts: col-major bf16 for MFMA B operands ----------------
__global__ void convert_win_kernel(const float* __restrict__ W, short* __restrict__ Wt) {
    int n = blockIdx.x;    // 0..95
    int k = threadIdx.x;   // 0..511
    Wt[(size_t)n * NFEAT + k] = (short)f2bf(W[(size_t)k * HID + n]);
}

__global__ void convert_wout_kernel(const float* __restrict__ W, short* __restrict__ Wt) {
    int n = blockIdx.x;    // 0..63
    int k = threadIdx.x;   // 0..95
    Wt[(size_t)n * HID + k] = (short)f2bf(W[(size_t)k * NCLASS + n]);
}

// ---------------- input GEMM via MFMA bf16, LDS-free / barrier-free ----------------
__global__ __launch_bounds__(256) void gemm_in_kernel(
        const float* __restrict__ x, const short* __restrict__ Wt,
        const float* __restrict__ b, short* __restrict__ h_bf, float* __restrict__ x0) {
    int tid  = threadIdx.x;
    int wave = tid >> 6, lane = tid & 63;
    int quad = lane >> 4, l16 = lane & 15;
    int row0 = blockIdx.x * 64 + wave * 16;   // wave's 16-row tile
    int arow = row0 + l16; if (arow >= N_NODES) arow = N_NODES - 1;
    const float* xrow = &x[(size_t)arow * NFEAT];

    f32x4 acc[6];
#pragma unroll
    for (int n = 0; n < 6; n++) acc[n] = (f32x4){0.f, 0.f, 0.f, 0.f};

#pragma unroll 4
    for (int k0 = 0; k0 < NFEAT; k0 += 32) {
        float4 v0 = *(const float4*)&xrow[k0 + quad * 8];
        float4 v1 = *(const float4*)&xrow[k0 + quad * 8 + 4];
        union { short8 s; uint4 u; } af;
        af.u.x = (unsigned)f2bf(v0.x) | ((unsigned)f2bf(v0.y) << 16);
        af.u.y = (unsigned)f2bf(v0.z) | ((unsigned)f2bf(v0.w) << 16);
        af.u.z = (unsigned)f2bf(v1.x) | ((unsigned)f2bf(v1.y) << 16);
        af.u.w = (unsigned)f2bf(v1.z) | ((unsigned)f2bf(v1.w) << 16);
#pragma unroll
        for (int n = 0; n < 6; n++) {
            short8 bfrag = *(const short8*)&Wt[(size_t)(n * 16 + l16) * NFEAT + k0 + quad * 8];
            acc[n] = __builtin_amdgcn_mfma_f32_16x16x32_bf16(af.s, bfrag, acc[n], 0, 0, 0);
        }
    }
#pragma unroll
    for (int n = 0; n < 6; n++) {
        int col = n * 16 + l16;
        float bias = b[col];
#pragma unroll
        for (int r = 0; r < 4; r++) {
            int grow = row0 + quad * 4 + r;
            if (grow < N_NODES) {
                float v = acc[n][r] + bias;
                v = v > 0.f ? v : 0.f;
                h_bf[(size_t)grow * HID + col] = (short)f2bf(v);
                x0[(size_t)grow * HID + col]   = v;
            }
        }
    }
}

// ---------------- fused layer: bf16 gather + residual mix + fp32 96x96 GEMM + relu -> bf16 --
__global__ __launch_bounds__(384) void layer_kernel(
        const short* __restrict__ h_in, const float* __restrict__ x0,
        const int* __restrict__ row_start, const int* __restrict__ deg,
        const int* __restrict__ csr_src, const int* __restrict__ perm,
        const float* __restrict__ W, float beta, short* __restrict__ h_out) {
    __shared__ float Ws[96][100];   // fp32 weights, padded
    __shared__ float As[32][100];   // hc fp32, padded
    int tx = threadIdx.x;           // 0..11
    int ty = threadIdx.y;           // 0..31
    int tid = ty * 12 + tx;
    int idx = blockIdx.x * 32 + ty;
    bool valid = idx < N_NODES;
    int node = valid ? perm[idx] : (N_NODES - 1);

#pragma unroll
    for (int j = 0; j < 6; j++) {
        int s = tid + j * 384;                  // float4 index, 2304 total
        int r = s / 24, cq = s % 24;
        *(float4*)&Ws[r][cq * 4] = ((const float4*)W)[s];
    }

    int s = row_start[node];
    int d = deg[node];
    int nq = (d + 3) >> 2;
    const int4* c4 = (const int4*)(csr_src + s);
    float acc[8];
#pragma unroll
    for (int j = 0; j < 8; j++) acc[j] = 0.f;
    for (int i = 0; i < nq; i++) {
        int4 idxv = c4[i];
        uint4 a0 = *(const uint4*)&h_in[(size_t)idxv.x * HID + tx * 8];
        uint4 a1 = *(const uint4*)&h_in[(size_t)idxv.y * HID + tx * 8];
        uint4 a2 = *(const uint4*)&h_in[(size_t)idxv.z * HID + tx * 8];
        uint4 a3 = *(const uint4*)&h_in[(size_t)idxv.w * HID + tx * 8];
        acc[0] += bflo(a0.x) + bflo(a1.x) + bflo(a2.x) + bflo(a3.x);
        acc[1] += bfhi(a0.x) + bfhi(a1.x) + bfhi(a2.x) + bfhi(a3.x);
        acc[2] += bflo(a0.y) + bflo(a1.y) + bflo(a2.y) + bflo(a3.y);
        acc[3] += bfhi(a0.y) + bfhi(a1.y) + bfhi(a2.y) + bfhi(a3.y);
        acc[4] += bflo(a0.z) + bflo(a1.z) + bflo(a2.z) + bflo(a3.z);
        acc[5] += bfhi(a0.z) + bfhi(a1.z) + bfhi(a2.z) + bfhi(a3.z);
        acc[6] += bflo(a0.w) + bflo(a1.w) + bflo(a2.w) + bflo(a3.w);
        acc[7] += bfhi(a0.w) + bfhi(a1.w) + bfhi(a2.w) + bfhi(a3.w);
    }
    float4 r0 = *(const float4*)&x0[(size_t)node * HID + tx * 8];
    float4 r1 = *(const float4*)&x0[(size_t)node * HID + tx * 8 + 4];
    float hc[8];
    hc[0] = (1.f - ALPHA) * acc[0] + ALPHA * r0.x;
    hc[1] = (1.f - ALPHA) * acc[1] + ALPHA * r0.y;
    hc[2] = (1.f - ALPHA) * acc[2] + ALPHA * r0.z;
    hc[3] = (1.f - ALPHA) * acc[3] + ALPHA * r0.w;
    hc[4] = (1.f - ALPHA) * acc[4] + ALPHA * r1.x;
    hc[5] = (1.f - ALPHA) * acc[5] + ALPHA * r1.y;
    hc[6] = (1.f - ALPHA) * acc[6] + ALPHA * r1.z;
    hc[7] = (1.f - ALPHA) * acc[7] + ALPHA * r1.w;
    *(float4*)&As[ty][tx * 8]     = *(float4*)&hc[0];
    *(float4*)&As[ty][tx * 8 + 4] = *(float4*)&hc[4];
    __syncthreads();

    int c0 = tx * 8;
    float g[8];
#pragma unroll
    for (int j = 0; j < 8; j++) g[j] = 0.f;
#pragma unroll 4
    for (int k = 0; k < 96; k++) {
        float a = As[ty][k];
        float4 w0 = *(const float4*)&Ws[k][c0];
        float4 w1 = *(const float4*)&Ws[k][c0 + 4];
        g[0] += a * w0.x; g[1] += a * w0.y; g[2] += a * w0.z; g[3] += a * w0.w;
        g[4] += a * w1.x; g[5] += a * w1.y; g[6] += a * w1.z; g[7] += a * w1.w;
    }
    if (valid) {
        float ob = 1.0f - beta;
        unsigned int pk[4];
#pragma unroll
        for (int j = 0; j < 4; j++) {
            float v0 = ob * hc[2*j]   + beta * g[2*j];
            float v1 = ob * hc[2*j+1] + beta * g[2*j+1];
            v0 = v0 > 0.f ? v0 : 0.f;
            v1 = v1 > 0.f ? v1 : 0.f;
            pk[j] = (unsigned)f2bf(v0) | ((unsigned)f2bf(v1) << 16);
        }
        *(uint4*)&h_out[(size_t)node * HID + c0] = *(uint4*)pk;
    }
}

// ---------------- output GEMM (MFMA bf16) + fused log_softmax ----------------
__global__ __launch_bounds__(256) void out_kernel(
        const short* __restrict__ h_bf, const short* __restrict__ Wt,
        const float* __restrict__ b, float* __restrict__ out) {
    int tid = threadIdx.x;
    int wave = tid >> 6, lane = tid & 63;
    int quad = lane >> 4, l16 = lane & 15;
    int row0 = blockIdx.x * 64 + wave * 16;

    f32x4 acc[4];
#pragma unroll
    for (int n = 0; n < 4; n++) acc[n] = (f32x4){0.f, 0.f, 0.f, 0.f};

    int arow = row0 + l16; if (arow > N_NODES) arow = N_NODES;  // dummy row is zero
#pragma unroll
    for (int ks = 0; ks < 3; ks++) {
        short8 afrag = *(const short8*)&h_bf[(size_t)arow * HID + ks * 32 + quad * 8];
#pragma unroll
        for (int n = 0; n < 4; n++) {
            short8 bfrag = *(const short8*)&Wt[(size_t)(n * 16 + l16) * HID + ks * 32 + quad * 8];
            acc[n] = __builtin_amdgcn_mfma_f32_16x16x32_bf16(afrag, bfrag, acc[n], 0, 0, 0);
        }
    }
#pragma unroll
    for (int n = 0; n < 4; n++) {
        float bias = b[n * 16 + l16];
#pragma unroll
        for (int r = 0; r < 4; r++) acc[n][r] += bias;
    }
#pragma unroll
    for (int r = 0; r < 4; r++) {
        float m = acc[0][r];
        m = fmaxf(m, acc[1][r]); m = fmaxf(m, acc[2][r]); m = fmaxf(m, acc[3][r]);
#pragma unroll
        for (int off = 1; off < 16; off <<= 1) m = fmaxf(m, __shfl_xor(m, off));
        float s = __expf(acc[0][r] - m) + __expf(acc[1][r] - m)
                + __expf(acc[2][r] - m) + __expf(acc[3][r] - m);
#pragma unroll
        for (int off = 1; off < 16; off <<= 1) s += __shfl_xor(s, off);
        float lse = m + __logf(s);
        int grow = row0 + quad * 4 + r;
        if (grow < N_NODES) {
#pragma unroll
            for (int n = 0; n < 4; n++)
                out[(size_t)grow * NCLASS + n * 16 + l16] = acc[n][r] - lse;
        }
    }
}

extern "C" void kernel_launch(void* const* d_in, const int* in_sizes, int n_in,
                              void* d_out, int out_size, void* d_ws, size_t ws_size,
                              hipStream_t stream) {
    const float* x      = (const float*)d_in[0];
    const int*   ei     = (const int*)d_in[1];
    const int*   srcp   = ei;
    const int*   dstp   = ei + N_EDGES;
    const float* W_in   = (const float*)d_in[2];
    const float* b_in   = (const float*)d_in[3];
    const float* conv_W = (const float*)d_in[4];
    const float* W_out  = (const float*)d_in[5];
    const float* b_out  = (const float*)d_in[6];
    float* out = (float*)d_out;

    short* h_a = (short*)d_ws;                               // (N+1) x HID bf16
    short* h_b = h_a + (size_t)(N_NODES + 1) * HID;
    float* x0  = (float*)(h_b + (size_t)(N_NODES + 1) * HID);
    short* Wt_in  = (short*)(x0 + (size_t)N_NODES * HID);    // 96 x 512
    short* Wt_out = Wt_in + (size_t)HID * NFEAT;             // 64 x 96
    int* deg        = (int*)(Wt_out + (size_t)NCLASS * HID);
    int* row_start  = deg + N_NODES;
    int* cursor     = row_start + N_NODES;
    int* blk_sum    = cursor + N_NODES;
    int* blk_off    = blk_sum + 64;
    int* bin_base   = blk_off + 64;
    int* node_rank  = bin_base + 64;
    int* perm       = node_rank + N_NODES;
    int* blk_bin_cnt= perm + N_NODES;                        // NBB*64
    int* blk_bin_off= blk_bin_cnt + NBB * 64;                // NBB*64
    int* csr_src    = blk_bin_off + NBB * 64;                // <= N_EDGES + 3*N_NODES ints

    hipMemsetAsync(deg,    0, N_NODES * sizeof(int), stream);
    hipMemsetAsync(cursor, 0, N_NODES * sizeof(int), stream);
    hist_kernel<<<(N_EDGES + 255) / 256, 256, 0, stream>>>(dstp, deg);
    scan1_kernel<<<NSB, 1024, 0, stream>>>(deg, row_start, blk_sum);
    scan2_kernel<<<1, 64, 0, stream>>>(blk_sum, blk_off);
    scan3_kernel<<<NSB, 1024, 0, stream>>>(row_start, blk_off);
    fill_kernel<<<(N_EDGES + 255) / 256, 256, 0, stream>>>(srcp, dstp, row_start, cursor, csr_src);
    pad_kernel<<<(N_NODES + 255) / 256, 256, 0, stream>>>(deg, row_start, csr_src);
    bin_hist2_kernel<<<NBB, 256, 0, stream>>>(deg, node_rank, blk_bin_cnt);
    bin_offsets_kernel<<<1, 64, 0, stream>>>(blk_bin_cnt, blk_bin_off, bin_base);
    bin_place_kernel<<<NBB, 256, 0, stream>>>(deg, node_rank, blk_bin_off, bin_base, perm);

    convert_win_kernel<<<HID, NFEAT, 0, stream>>>(W_in, Wt_in);
    convert_wout_kernel<<<NCLASS, HID, 0, stream>>>(W_out, Wt_out);
    gemm_in_kernel<<<(N_NODES + 63) / 64, 256, 0, stream>>>(x, Wt_in, b_in, h_a, x0);
    zero_dummy_kernel<<<1, 128, 0, stream>>>(h_a, h_b);

    short* cur = h_a;
    short* nxt = h_b;
    for (int l = 0; l < NUM_LAYERS; l++) {
        float beta = logf(0.5f / (float)(l + 1) + 1.0f);
        layer_kernel<<<(N_NODES + 31) / 32, dim3(12, 32), 0, stream>>>(
            cur, x0, row_start, deg, csr_src, perm, conv_W + (size_t)l * HID * HID, beta, nxt);
        short* t = cur; cur = nxt; nxt = t;
    }

    out_kernel<<<(N_NODES + 63) / 64, 256, 0, stream>>>(cur, Wt_out, b_out, out);
}

// Round 8
// 681.520 us; speedup vs baseline: 1.8593x; 1.0099x over previous
//
#include <hip/hip_runtime.h>
#include <math.h>

#define N_NODES 50000
#define N_EDGES 800000
#define NFEAT   512
#define HID     96
#define NCLASS  64
#define NUM_LAYERS 8
#define ALPHA   0.1f
#define NSB     49          // scan blocks: ceil(50000/1024)
#define NBB     196         // bin blocks: ceil(50000/256)

typedef __attribute__((ext_vector_type(8))) short short8;
typedef __attribute__((ext_vector_type(4))) float f32x4;

__device__ __forceinline__ unsigned short f2bf(float f) {
    unsigned int u = __float_as_uint(f);
    unsigned int r = u + 0x7FFF + ((u >> 16) & 1);   // round-to-nearest-even
    return (unsigned short)(r >> 16);
}
__device__ __forceinline__ float bflo(unsigned int u) { return __uint_as_float(u << 16); }
__device__ __forceinline__ float bfhi(unsigned int u) { return __uint_as_float(u & 0xFFFF0000u); }

// ---------------- CSR build (rows padded to multiple of 4, dummy = N_NODES) ----------------
__global__ void hist_kernel(const int* __restrict__ dst, int* __restrict__ deg) {
    int e = blockIdx.x * blockDim.x + threadIdx.x;
    if (e < N_EDGES) atomicAdd(&deg[dst[e]], 1);
}

__global__ void scan1_kernel(const int* __restrict__ deg, int* __restrict__ row_start,
                             int* __restrict__ blk_sum) {
    __shared__ int sd[1024];
    int t = threadIdx.x;
    int i = blockIdx.x * 1024 + t;
    int v = (i < N_NODES) ? ((deg[i] + 3) & ~3) : 0;   // padded degree
    sd[t] = v;
    __syncthreads();
    for (int off = 1; off < 1024; off <<= 1) {
        int tv = (t >= off) ? sd[t - off] : 0;
        __syncthreads();
        sd[t] += tv;
        __syncthreads();
    }
    if (i < N_NODES) row_start[i] = sd[t] - v;          // exclusive, block-local
    if (t == 1023) blk_sum[blockIdx.x] = sd[1023];
}

__global__ void scan2_kernel(const int* __restrict__ blk_sum, int* __restrict__ blk_off) {
    if (threadIdx.x == 0) {
        int acc = 0;
        for (int b = 0; b < NSB; b++) { blk_off[b] = acc; acc += blk_sum[b]; }
    }
}

__global__ void scan3_kernel(int* __restrict__ row_start, const int* __restrict__ blk_off) {
    int i = blockIdx.x * 1024 + threadIdx.x;
    if (i < N_NODES) row_start[i] += blk_off[blockIdx.x];
}

__global__ void fill_kernel(const int* __restrict__ src, const int* __restrict__ dst,
                            const int* __restrict__ row_start, int* __restrict__ cursor,
                            int* __restrict__ csr_src) {
    int e = blockIdx.x * blockDim.x + threadIdx.x;
    if (e < N_EDGES) {
        int d = dst[e];
        int pos = row_start[d] + atomicAdd(&cursor[d], 1);
        csr_src[pos] = src[e];
    }
}

__global__ void pad_kernel(const int* __restrict__ deg, const int* __restrict__ row_start,
                           int* __restrict__ csr_src) {
    int n = blockIdx.x * blockDim.x + threadIdx.x;
    if (n < N_NODES) {
        int d = deg[n], pd = (d + 3) & ~3, rs = row_start[n];
        for (int p = d; p < pd; p++) csr_src[rs + p] = N_NODES;  // dummy zero row
    }
}

// -------- degree-bucket permutation, contention-free counting sort (3 passes) --------
__global__ __launch_bounds__(256) void bin_hist2_kernel(
        const int* __restrict__ deg, int* __restrict__ node_rank,
        int* __restrict__ blk_bin_cnt) {
    __shared__ int lh[64];
    int t = threadIdx.x;
    if (t < 64) lh[t] = 0;
    __syncthreads();
    int n = blockIdx.x * 256 + t;
    if (n < N_NODES) {
        int nq = (deg[n] + 3) >> 2; if (nq > 63) nq = 63;
        node_rank[n] = atomicAdd(&lh[nq], 1);      // LDS atomic: block-private
    }
    __syncthreads();
    if (t < 64) blk_bin_cnt[blockIdx.x * 64 + t] = lh[t];
}

__global__ void bin_offsets_kernel(const int* __restrict__ blk_bin_cnt,
                                   int* __restrict__ blk_bin_off,
                                   int* __restrict__ bin_base) {
    __shared__ int tot[64];
    int b = threadIdx.x;  // 0..63
    int acc = 0;
    for (int blk = 0; blk < NBB; blk++) {
        blk_bin_off[blk * 64 + b] = acc;
        acc += blk_bin_cnt[blk * 64 + b];
    }
    tot[b] = acc;
    __syncthreads();
    if (b == 0) {
        int a = 0;
        for (int i = 63; i >= 0; i--) { bin_base[i] = a; a += tot[i]; }
    }
}

__global__ __launch_bounds__(256) void bin_place_kernel(
        const int* __restrict__ deg, const int* __restrict__ node_rank,
        const int* __restrict__ blk_bin_off, const int* __restrict__ bin_base,
        int* __restrict__ perm) {
    int n = blockIdx.x * 256 + threadIdx.x;
    if (n < N_NODES) {
        int nq = (deg[n] + 3) >> 2; if (nq > 63) nq = 63;
        perm[bin_base[nq] + blk_bin_off[blockIdx.x * 64 + nq] + node_rank[n]] = n;
    }
}

__global__ void zero_dummy_kernel(short* __restrict__ h0, short* __restrict__ hb,
                                  short* __restrict__ hc) {
    int t = threadIdx.x;
    if (t < HID) {
        h0[(size_t)N_NODES * HID + t] = 0;
        hb[(size_t)N_NODES * HID + t] = 0;
        hc[(size_t)N_NODES * HID + t] = 0;
    }
}

// ---------------- weight converts: col-major bf16 for MFMA B operands ----------------
__global__ void convert_win_kernel(const float* __restrict__ W, short* __restrict__ Wt) {
    int n = blockIdx.x;    // 0..95
    int k = threadIdx.x;   // 0..511
    Wt[(size_t)n * NFEAT + k] = (short)f2bf(W[(size_t)k * HID + n]);
}

__global__ void convert_wout_kernel(const float* __restrict__ W, short* __restrict__ Wt) {
    int n = blockIdx.x;    // 0..63
    int k = threadIdx.x;   // 0..95
    Wt[(size_t)n * HID + k] = (short)f2bf(W[(size_t)k * NCLASS + n]);
}

// ---------------- input GEMM via MFMA bf16, barrier-free, manually pipelined ----------
// Wave owns 16 rows exclusively; next K-step's A (global) and B (L2) fragments are
// loaded while the current step's 6 MFMAs issue. Writes bf16 h0 only (h0 == x0).
__global__ __launch_bounds__(256) void gemm_in_kernel(
        const float* __restrict__ x, const short* __restrict__ Wt,
        const float* __restrict__ b, short* __restrict__ h0) {
    int tid  = threadIdx.x;
    int wave = tid >> 6, lane = tid & 63;
    int quad = lane >> 4, l16 = lane & 15;
    int row0 = blockIdx.x * 64 + wave * 16;   // wave's 16-row tile
    int arow = row0 + l16; if (arow >= N_NODES) arow = N_NODES - 1;
    const float* xrow = &x[(size_t)arow * NFEAT];
    const short* wrow = &Wt[(size_t)l16 * NFEAT + quad * 8];

    f32x4 acc[6];
#pragma unroll
    for (int n = 0; n < 6; n++) acc[n] = (f32x4){0.f, 0.f, 0.f, 0.f};

    // preload K-step 0
    float4 v0 = *(const float4*)&xrow[quad * 8];
    float4 v1 = *(const float4*)&xrow[quad * 8 + 4];
    short8 bc[6];
#pragma unroll
    for (int n = 0; n < 6; n++) bc[n] = *(const short8*)&wrow[(size_t)n * 16 * NFEAT];

#pragma unroll
    for (int k0 = 0; k0 < NFEAT; k0 += 32) {
        float4 nv0, nv1;
        short8 bn[6];
        if (k0 + 32 < NFEAT) {      // compile-time per unrolled iteration
            nv0 = *(const float4*)&xrow[k0 + 32 + quad * 8];
            nv1 = *(const float4*)&xrow[k0 + 32 + quad * 8 + 4];
#pragma unroll
            for (int n = 0; n < 6; n++)
                bn[n] = *(const short8*)&wrow[(size_t)n * 16 * NFEAT + k0 + 32];
        }
        union { short8 s; uint4 u; } af;
        af.u.x = (unsigned)f2bf(v0.x) | ((unsigned)f2bf(v0.y) << 16);
        af.u.y = (unsigned)f2bf(v0.z) | ((unsigned)f2bf(v0.w) << 16);
        af.u.z = (unsigned)f2bf(v1.x) | ((unsigned)f2bf(v1.y) << 16);
        af.u.w = (unsigned)f2bf(v1.z) | ((unsigned)f2bf(v1.w) << 16);
#pragma unroll
        for (int n = 0; n < 6; n++)
            acc[n] = __builtin_amdgcn_mfma_f32_16x16x32_bf16(af.s, bc[n], acc[n], 0, 0, 0);
        if (k0 + 32 < NFEAT) {
            v0 = nv0; v1 = nv1;
#pragma unroll
            for (int n = 0; n < 6; n++) bc[n] = bn[n];
        }
    }
#pragma unroll
    for (int n = 0; n < 6; n++) {
        int col = n * 16 + l16;
        float bias = b[col];
#pragma unroll
        for (int r = 0; r < 4; r++) {
            int grow = row0 + quad * 4 + r;
            if (grow < N_NODES) {
                float v = acc[n][r] + bias;
                v = v > 0.f ? v : 0.f;
                h0[(size_t)grow * HID + col] = (short)f2bf(v);
            }
        }
    }
}

// ---------------- fused layer: bf16 gather + residual mix + fp32 96x96 GEMM + relu -> bf16 --
// block (12,32): ty = node slot (degree-sorted via perm), tx = 8-feature chunk. 16B gathers.
__global__ __launch_bounds__(384) void layer_kernel(
        const short* __restrict__ h_in, const short* __restrict__ x0bf,
        const int* __restrict__ row_start, const int* __restrict__ deg,
        const int* __restrict__ csr_src, const int* __restrict__ perm,
        const float* __restrict__ W, float beta, short* __restrict__ h_out) {
    __shared__ float Ws[96][100];   // fp32 weights, padded
    __shared__ float As[32][100];   // hc fp32, padded
    int tx = threadIdx.x;           // 0..11
    int ty = threadIdx.y;           // 0..31
    int tid = ty * 12 + tx;
    int idx = blockIdx.x * 32 + ty;
    bool valid = idx < N_NODES;
    int node = valid ? perm[idx] : (N_NODES - 1);

#pragma unroll
    for (int j = 0; j < 6; j++) {
        int s = tid + j * 384;                  // float4 index, 2304 total
        int r = s / 24, cq = s % 24;
        *(float4*)&Ws[r][cq * 4] = ((const float4*)W)[s];
    }

    int s = row_start[node];
    int d = deg[node];
    int nq = (d + 3) >> 2;
    const int4* c4 = (const int4*)(csr_src + s);
    float acc[8];
#pragma unroll
    for (int j = 0; j < 8; j++) acc[j] = 0.f;
    for (int i = 0; i < nq; i++) {
        int4 idxv = c4[i];
        uint4 a0 = *(const uint4*)&h_in[(size_t)idxv.x * HID + tx * 8];
        uint4 a1 = *(const uint4*)&h_in[(size_t)idxv.y * HID + tx * 8];
        uint4 a2 = *(const uint4*)&h_in[(size_t)idxv.z * HID + tx * 8];
        uint4 a3 = *(const uint4*)&h_in[(size_t)idxv.w * HID + tx * 8];
        acc[0] += bflo(a0.x) + bflo(a1.x) + bflo(a2.x) + bflo(a3.x);
        acc[1] += bfhi(a0.x) + bfhi(a1.x) + bfhi(a2.x) + bfhi(a3.x);
        acc[2] += bflo(a0.y) + bflo(a1.y) + bflo(a2.y) + bflo(a3.y);
        acc[3] += bfhi(a0.y) + bfhi(a1.y) + bfhi(a2.y) + bfhi(a3.y);
        acc[4] += bflo(a0.z) + bflo(a1.z) + bflo(a2.z) + bflo(a3.z);
        acc[5] += bfhi(a0.z) + bfhi(a1.z) + bfhi(a2.z) + bfhi(a3.z);
        acc[6] += bflo(a0.w) + bflo(a1.w) + bflo(a2.w) + bflo(a3.w);
        acc[7] += bfhi(a0.w) + bfhi(a1.w) + bfhi(a2.w) + bfhi(a3.w);
    }
    uint4 xq = *(const uint4*)&x0bf[(size_t)node * HID + tx * 8];
    float hc[8];
    hc[0] = (1.f - ALPHA) * acc[0] + ALPHA * bflo(xq.x);
    hc[1] = (1.f - ALPHA) * acc[1] + ALPHA * bfhi(xq.x);
    hc[2] = (1.f - ALPHA) * acc[2] + ALPHA * bflo(xq.y);
    hc[3] = (1.f - ALPHA) * acc[3] + ALPHA * bfhi(xq.y);
    hc[4] = (1.f - ALPHA) * acc[4] + ALPHA * bflo(xq.z);
    hc[5] = (1.f - ALPHA) * acc[5] + ALPHA * bfhi(xq.z);
    hc[6] = (1.f - ALPHA) * acc[6] + ALPHA * bflo(xq.w);
    hc[7] = (1.f - ALPHA) * acc[7] + ALPHA * bfhi(xq.w);
    *(float4*)&As[ty][tx * 8]     = *(float4*)&hc[0];
    *(float4*)&As[ty][tx * 8 + 4] = *(float4*)&hc[4];
    __syncthreads();

    int c0 = tx * 8;
    float g[8];
#pragma unroll
    for (int j = 0; j < 8; j++) g[j] = 0.f;
#pragma unroll 4
    for (int k = 0; k < 96; k++) {
        float a = As[ty][k];
        float4 w0 = *(const float4*)&Ws[k][c0];
        float4 w1 = *(const float4*)&Ws[k][c0 + 4];
        g[0] += a * w0.x; g[1] += a * w0.y; g[2] += a * w0.z; g[3] += a * w0.w;
        g[4] += a * w1.x; g[5] += a * w1.y; g[6] += a * w1.z; g[7] += a * w1.w;
    }
    if (valid) {
        float ob = 1.0f - beta;
        unsigned int pk[4];
#pragma unroll
        for (int j = 0; j < 4; j++) {
            float v0 = ob * hc[2*j]   + beta * g[2*j];
            float v1 = ob * hc[2*j+1] + beta * g[2*j+1];
            v0 = v0 > 0.f ? v0 : 0.f;
            v1 = v1 > 0.f ? v1 : 0.f;
            pk[j] = (unsigned)f2bf(v0) | ((unsigned)f2bf(v1) << 16);
        }
        *(uint4*)&h_out[(size_t)node * HID + c0] = *(uint4*)pk;
    }
}

// ---------------- output GEMM (MFMA bf16) + fused log_softmax ----------------
__global__ __launch_bounds__(256) void out_kernel(
        const short* __restrict__ h_bf, const short* __restrict__ Wt,
        const float* __restrict__ b, float* __restrict__ out) {
    int tid = threadIdx.x;
    int wave = tid >> 6, lane = tid & 63;
    int quad = lane >> 4, l16 = lane & 15;
    int row0 = blockIdx.x * 64 + wave * 16;

    f32x4 acc[4];
#pragma unroll
    for (int n = 0; n < 4; n++) acc[n] = (f32x4){0.f, 0.f, 0.f, 0.f};

    int arow = row0 + l16; if (arow > N_NODES) arow = N_NODES;  // dummy row is zero
#pragma unroll
    for (int ks = 0; ks < 3; ks++) {
        short8 afrag = *(const short8*)&h_bf[(size_t)arow * HID + ks * 32 + quad * 8];
#pragma unroll
        for (int n = 0; n < 4; n++) {
            short8 bfrag = *(const short8*)&Wt[(size_t)(n * 16 + l16) * HID + ks * 32 + quad * 8];
            acc[n] = __builtin_amdgcn_mfma_f32_16x16x32_bf16(afrag, bfrag, acc[n], 0, 0, 0);
        }
    }
#pragma unroll
    for (int n = 0; n < 4; n++) {
        float bias = b[n * 16 + l16];
#pragma unroll
        for (int r = 0; r < 4; r++) acc[n][r] += bias;
    }
#pragma unroll
    for (int r = 0; r < 4; r++) {
        float m = acc[0][r];
        m = fmaxf(m, acc[1][r]); m = fmaxf(m, acc[2][r]); m = fmaxf(m, acc[3][r]);
#pragma unroll
        for (int off = 1; off < 16; off <<= 1) m = fmaxf(m, __shfl_xor(m, off));
        float s = __expf(acc[0][r] - m) + __expf(acc[1][r] - m)
                + __expf(acc[2][r] - m) + __expf(acc[3][r] - m);
#pragma unroll
        for (int off = 1; off < 16; off <<= 1) s += __shfl_xor(s, off);
        float lse = m + __logf(s);
        int grow = row0 + quad * 4 + r;
        if (grow < N_NODES) {
#pragma unroll
            for (int n = 0; n < 4; n++)
                out[(size_t)grow * NCLASS + n * 16 + l16] = acc[n][r] - lse;
        }
    }
}

extern "C" void kernel_launch(void* const* d_in, const int* in_sizes, int n_in,
                              void* d_out, int out_size, void* d_ws, size_t ws_size,
                              hipStream_t stream) {
    const float* x      = (const float*)d_in[0];
    const int*   ei     = (const int*)d_in[1];
    const int*   srcp   = ei;
    const int*   dstp   = ei + N_EDGES;
    const float* W_in   = (const float*)d_in[2];
    const float* b_in   = (const float*)d_in[3];
    const float* conv_W = (const float*)d_in[4];
    const float* W_out  = (const float*)d_in[5];
    const float* b_out  = (const float*)d_in[6];
    float* out = (float*)d_out;

    short* h0  = (short*)d_ws;                               // (N+1) x HID bf16 == x0
    short* h_b = h0  + (size_t)(N_NODES + 1) * HID;
    short* h_c = h_b + (size_t)(N_NODES + 1) * HID;
    short* Wt_in  = h_c + (size_t)(N_NODES + 1) * HID;       // 96 x 512
    short* Wt_out = Wt_in + (size_t)HID * NFEAT;             // 64 x 96
    int* deg        = (int*)(Wt_out + (size_t)NCLASS * HID);
    int* row_start  = deg + N_NODES;
    int* cursor     = row_start + N_NODES;
    int* blk_sum    = cursor + N_NODES;
    int* blk_off    = blk_sum + 64;
    int* bin_base   = blk_off + 64;
    int* node_rank  = bin_base + 64;
    int* perm       = node_rank + N_NODES;
    int* blk_bin_cnt= perm + N_NODES;                        // NBB*64
    int* blk_bin_off= blk_bin_cnt + NBB * 64;                // NBB*64
    int* csr_src    = blk_bin_off + NBB * 64;                // <= N_EDGES + 3*N_NODES ints

    hipMemsetAsync(deg,    0, N_NODES * sizeof(int), stream);
    hipMemsetAsync(cursor, 0, N_NODES * sizeof(int), stream);
    hist_kernel<<<(N_EDGES + 255) / 256, 256, 0, stream>>>(dstp, deg);
    scan1_kernel<<<NSB, 1024, 0, stream>>>(deg, row_start, blk_sum);
    scan2_kernel<<<1, 64, 0, stream>>>(blk_sum, blk_off);
    scan3_kernel<<<NSB, 1024, 0, stream>>>(row_start, blk_off);
    fill_kernel<<<(N_EDGES + 255) / 256, 256, 0, stream>>>(srcp, dstp, row_start, cursor, csr_src);
    pad_kernel<<<(N_NODES + 255) / 256, 256, 0, stream>>>(deg, row_start, csr_src);
    bin_hist2_kernel<<<NBB, 256, 0, stream>>>(deg, node_rank, blk_bin_cnt);
    bin_offsets_kernel<<<1, 64, 0, stream>>>(blk_bin_cnt, blk_bin_off, bin_base);
    bin_place_kernel<<<NBB, 256, 0, stream>>>(deg, node_rank, blk_bin_off, bin_base, perm);

    convert_win_kernel<<<HID, NFEAT, 0, stream>>>(W_in, Wt_in);
    convert_wout_kernel<<<NCLASS, HID, 0, stream>>>(W_out, Wt_out);
    gemm_in_kernel<<<(N_NODES + 63) / 64, 256, 0, stream>>>(x, Wt_in, b_in, h0);
    zero_dummy_kernel<<<1, 128, 0, stream>>>(h0, h_b, h_c);

    short* cur = h0;
    short* nxt = h_b;
    for (int l = 0; l < NUM_LAYERS; l++) {
        float beta = logf(0.5f / (float)(l + 1) + 1.0f);
        layer_kernel<<<(N_NODES + 31) / 32, dim3(12, 32), 0, stream>>>(
            cur, h0, row_start, deg, csr_src, perm, conv_W + (size_t)l * HID * HID, beta, nxt);
        cur = nxt;
        nxt = (cur == h_b) ? h_c : h_b;
    }

    out_kernel<<<(N_NODES + 63) / 64, 256, 0, stream>>>(cur, Wt_out, b_out, out);
}

// Round 9
// 563.258 us; speedup vs baseline: 2.2497x; 1.2100x over previous
//
#include <hip/hip_runtime.h>
#include <math.h>

#define N_NODES 50000
#define N_EDGES 800000
#define NFEAT   512
#define HID     96
#define NCLASS  64
#define NUM_LAYERS 8
#define ALPHA   0.1f
#define NSB     49          // scan blocks: ceil(50000/1024)
#define NBB     196         // bin blocks: ceil(50000/256)

typedef __attribute__((ext_vector_type(8))) short short8;
typedef __attribute__((ext_vector_type(4))) float f32x4;

__device__ __forceinline__ unsigned short f2bf(float f) {
    unsigned int u = __float_as_uint(f);
    unsigned int r = u + 0x7FFF + ((u >> 16) & 1);   // round-to-nearest-even
    return (unsigned short)(r >> 16);
}
__device__ __forceinline__ float bflo(unsigned int u) { return __uint_as_float(u << 16); }
__device__ __forceinline__ float bfhi(unsigned int u) { return __uint_as_float(u & 0xFFFF0000u); }
__device__ __forceinline__ float bf2f(short s) {
    return __uint_as_float(((unsigned int)(unsigned short)s) << 16);
}

// ---------------- CSR build (rows padded to multiple of 4, dummy = N_NODES) ----------------
__global__ void hist_kernel(const int* __restrict__ dst, int* __restrict__ deg) {
    int e = blockIdx.x * blockDim.x + threadIdx.x;
    if (e < N_EDGES) atomicAdd(&deg[dst[e]], 1);
}

__global__ void scan1_kernel(const int* __restrict__ deg, int* __restrict__ row_start,
                             int* __restrict__ blk_sum) {
    __shared__ int sd[1024];
    int t = threadIdx.x;
    int i = blockIdx.x * 1024 + t;
    int v = (i < N_NODES) ? ((deg[i] + 3) & ~3) : 0;   // padded degree
    sd[t] = v;
    __syncthreads();
    for (int off = 1; off < 1024; off <<= 1) {
        int tv = (t >= off) ? sd[t - off] : 0;
        __syncthreads();
        sd[t] += tv;
        __syncthreads();
    }
    if (i < N_NODES) row_start[i] = sd[t] - v;          // exclusive, block-local
    if (t == 1023) blk_sum[blockIdx.x] = sd[1023];
}

__global__ void scan2_kernel(const int* __restrict__ blk_sum, int* __restrict__ blk_off) {
    if (threadIdx.x == 0) {
        int acc = 0;
        for (int b = 0; b < NSB; b++) { blk_off[b] = acc; acc += blk_sum[b]; }
    }
}

__global__ void scan3_kernel(int* __restrict__ row_start, const int* __restrict__ blk_off) {
    int i = blockIdx.x * 1024 + threadIdx.x;
    if (i < N_NODES) row_start[i] += blk_off[blockIdx.x];
}

__global__ void fill_kernel(const int* __restrict__ src, const int* __restrict__ dst,
                            const int* __restrict__ row_start, int* __restrict__ cursor,
                            int* __restrict__ csr_src) {
    int e = blockIdx.x * blockDim.x + threadIdx.x;
    if (e < N_EDGES) {
        int d = dst[e];
        int pos = row_start[d] + atomicAdd(&cursor[d], 1);
        csr_src[pos] = src[e];
    }
}

__global__ void pad_kernel(const int* __restrict__ deg, const int* __restrict__ row_start,
                           int* __restrict__ csr_src) {
    int n = blockIdx.x * blockDim.x + threadIdx.x;
    if (n < N_NODES) {
        int d = deg[n], pd = (d + 3) & ~3, rs = row_start[n];
        for (int p = d; p < pd; p++) csr_src[rs + p] = N_NODES;  // dummy zero row
    }
}

// -------- degree-bucket permutation, contention-free counting sort (3 passes) --------
__global__ __launch_bounds__(256) void bin_hist2_kernel(
        const int* __restrict__ deg, int* __restrict__ node_rank,
        int* __restrict__ blk_bin_cnt) {
    __shared__ int lh[64];
    int t = threadIdx.x;
    if (t < 64) lh[t] = 0;
    __syncthreads();
    int n = blockIdx.x * 256 + t;
    if (n < N_NODES) {
        int nq = (deg[n] + 3) >> 2; if (nq > 63) nq = 63;
        node_rank[n] = atomicAdd(&lh[nq], 1);      // LDS atomic: block-private
    }
    __syncthreads();
    if (t < 64) blk_bin_cnt[blockIdx.x * 64 + t] = lh[t];
}

__global__ void bin_offsets_kernel(const int* __restrict__ blk_bin_cnt,
                                   int* __restrict__ blk_bin_off,
                                   int* __restrict__ bin_base) {
    __shared__ int tot[64];
    int b = threadIdx.x;  // 0..63
    int acc = 0;
    for (int blk = 0; blk < NBB; blk++) {
        blk_bin_off[blk * 64 + b] = acc;
        acc += blk_bin_cnt[blk * 64 + b];
    }
    tot[b] = acc;
    __syncthreads();
    if (b == 0) {
        int a = 0;
        for (int i = 63; i >= 0; i--) { bin_base[i] = a; a += tot[i]; }
    }
}

__global__ __launch_bounds__(256) void bin_place_kernel(
        const int* __restrict__ deg, const int* __restrict__ node_rank,
        const int* __restrict__ blk_bin_off, const int* __restrict__ bin_base,
        int* __restrict__ perm) {
    int n = blockIdx.x * 256 + threadIdx.x;
    if (n < N_NODES) {
        int nq = (deg[n] + 3) >> 2; if (nq > 63) nq = 63;
        perm[bin_base[nq] + blk_bin_off[blockIdx.x * 64 + nq] + node_rank[n]] = n;
    }
}

__global__ void zero_dummy_kernel(short* __restrict__ h0, short* __restrict__ hb,
                                  short* __restrict__ hc) {
    int t = threadIdx.x;
    if (t < HID) {
        h0[(size_t)N_NODES * HID + t] = 0;
        hb[(size_t)N_NODES * HID + t] = 0;
        hc[(size_t)N_NODES * HID + t] = 0;
    }
}

// ---------------- weight converts: col-major bf16 for MFMA B operands ----------------
__global__ void convert_win_kernel(const float* __restrict__ W, short* __restrict__ Wt) {
    int n = blockIdx.x;    // 0..95
    int k = threadIdx.x;   // 0..511
    Wt[(size_t)n * NFEAT + k] = (short)f2bf(W[(size_t)k * HID + n]);
}

__global__ void convert_wout_kernel(const float* __restrict__ W, short* __restrict__ Wt) {
    int n = blockIdx.x;    // 0..63
    int k = threadIdx.x;   // 0..95
    Wt[(size_t)n * HID + k] = (short)f2bf(W[(size_t)k * NCLASS + n]);
}

// conv_W[l][k][n] fp32 -> Wc[l][n][k] bf16 (col-major per layer)
__global__ void convert_wconv_kernel(const float* __restrict__ W, short* __restrict__ Wc) {
    int n = blockIdx.x;    // 0..95
    int l = blockIdx.y;    // 0..7
    int k = threadIdx.x;   // 0..95
    Wc[(size_t)l * HID * HID + (size_t)n * HID + k] =
        (short)f2bf(W[(size_t)l * HID * HID + (size_t)k * HID + n]);
}

// ---------------- input GEMM via MFMA bf16, barrier-free ----------
__global__ __launch_bounds__(256) void gemm_in_kernel(
        const float* __restrict__ x, const short* __restrict__ Wt,
        const float* __restrict__ b, short* __restrict__ h0) {
    int tid  = threadIdx.x;
    int wave = tid >> 6, lane = tid & 63;
    int quad = lane >> 4, l16 = lane & 15;
    int row0 = blockIdx.x * 64 + wave * 16;   // wave's 16-row tile
    int arow = row0 + l16; if (arow >= N_NODES) arow = N_NODES - 1;
    const float* xrow = &x[(size_t)arow * NFEAT];
    const short* wrow = &Wt[(size_t)l16 * NFEAT + quad * 8];

    f32x4 acc[6];
#pragma unroll
    for (int n = 0; n < 6; n++) acc[n] = (f32x4){0.f, 0.f, 0.f, 0.f};

#pragma unroll
    for (int k0 = 0; k0 < NFEAT; k0 += 32) {
        float4 v0 = *(const float4*)&xrow[k0 + quad * 8];
        float4 v1 = *(const float4*)&xrow[k0 + quad * 8 + 4];
        union { short8 s; uint4 u; } af;
        af.u.x = (unsigned)f2bf(v0.x) | ((unsigned)f2bf(v0.y) << 16);
        af.u.y = (unsigned)f2bf(v0.z) | ((unsigned)f2bf(v0.w) << 16);
        af.u.z = (unsigned)f2bf(v1.x) | ((unsigned)f2bf(v1.y) << 16);
        af.u.w = (unsigned)f2bf(v1.z) | ((unsigned)f2bf(v1.w) << 16);
#pragma unroll
        for (int n = 0; n < 6; n++) {
            short8 bfrag = *(const short8*)&wrow[(size_t)n * 16 * NFEAT + k0];
            acc[n] = __builtin_amdgcn_mfma_f32_16x16x32_bf16(af.s, bfrag, acc[n], 0, 0, 0);
        }
    }
#pragma unroll
    for (int n = 0; n < 6; n++) {
        int col = n * 16 + l16;
        float bias = b[col];
#pragma unroll
        for (int r = 0; r < 4; r++) {
            int grow = row0 + quad * 4 + r;
            if (grow < N_NODES) {
                float v = acc[n][r] + bias;
                v = v > 0.f ? v : 0.f;
                h0[(size_t)grow * HID + col] = (short)f2bf(v);
            }
        }
    }
}

// ---------------- fused layer v2: bf16 gather + residual mix (fp32) -> bf16 LDS,
// then MFMA 96x96 conv with B from L2, epilogue residual+relu, permuted scatter ----
// block = 384 threads. Phase 1: (tx=12, ty=32) gather. Phase 2: 6 waves x 2 MFMA tasks.
__global__ __launch_bounds__(384) void layer_kernel(
        const short* __restrict__ h_in, const short* __restrict__ x0bf,
        const int* __restrict__ row_start, const int* __restrict__ deg,
        const int* __restrict__ csr_src, const int* __restrict__ perm,
        const short* __restrict__ Wc, float beta, short* __restrict__ h_out) {
    __shared__ short As[32][104];   // hc bf16, row stride 104 shorts (208 B)
    __shared__ int   snode[32];
    int tid = threadIdx.x;
    int tx = tid % 12;              // feature chunk
    int ty = tid / 12;              // node slot 0..31
    int idx = blockIdx.x * 32 + ty;
    bool valid = idx < N_NODES;
    int node = valid ? perm[idx] : (N_NODES - 1);
    if (tx == 0) snode[ty] = valid ? node : -1;

    int s = row_start[node];
    int d = deg[node];
    int nq = (d + 3) >> 2;
    const int4* c4 = (const int4*)(csr_src + s);
    float acc[8];
#pragma unroll
    for (int j = 0; j < 8; j++) acc[j] = 0.f;
    for (int i = 0; i < nq; i++) {
        int4 idxv = c4[i];
        uint4 a0 = *(const uint4*)&h_in[(size_t)idxv.x * HID + tx * 8];
        uint4 a1 = *(const uint4*)&h_in[(size_t)idxv.y * HID + tx * 8];
        uint4 a2 = *(const uint4*)&h_in[(size_t)idxv.z * HID + tx * 8];
        uint4 a3 = *(const uint4*)&h_in[(size_t)idxv.w * HID + tx * 8];
        acc[0] += bflo(a0.x) + bflo(a1.x) + bflo(a2.x) + bflo(a3.x);
        acc[1] += bfhi(a0.x) + bfhi(a1.x) + bfhi(a2.x) + bfhi(a3.x);
        acc[2] += bflo(a0.y) + bflo(a1.y) + bflo(a2.y) + bflo(a3.y);
        acc[3] += bfhi(a0.y) + bfhi(a1.y) + bfhi(a2.y) + bfhi(a3.y);
        acc[4] += bflo(a0.z) + bflo(a1.z) + bflo(a2.z) + bflo(a3.z);
        acc[5] += bfhi(a0.z) + bfhi(a1.z) + bfhi(a2.z) + bfhi(a3.z);
        acc[6] += bflo(a0.w) + bflo(a1.w) + bflo(a2.w) + bflo(a3.w);
        acc[7] += bfhi(a0.w) + bfhi(a1.w) + bfhi(a2.w) + bfhi(a3.w);
    }
    uint4 xq = *(const uint4*)&x0bf[(size_t)node * HID + tx * 8];
    float hc[8];
    hc[0] = (1.f - ALPHA) * acc[0] + ALPHA * bflo(xq.x);
    hc[1] = (1.f - ALPHA) * acc[1] + ALPHA * bfhi(xq.x);
    hc[2] = (1.f - ALPHA) * acc[2] + ALPHA * bflo(xq.y);
    hc[3] = (1.f - ALPHA) * acc[3] + ALPHA * bfhi(xq.y);
    hc[4] = (1.f - ALPHA) * acc[4] + ALPHA * bflo(xq.z);
    hc[5] = (1.f - ALPHA) * acc[5] + ALPHA * bfhi(xq.z);
    hc[6] = (1.f - ALPHA) * acc[6] + ALPHA * bflo(xq.w);
    hc[7] = (1.f - ALPHA) * acc[7] + ALPHA * bfhi(xq.w);
    {
        uint4 pk;
        pk.x = (unsigned)f2bf(hc[0]) | ((unsigned)f2bf(hc[1]) << 16);
        pk.y = (unsigned)f2bf(hc[2]) | ((unsigned)f2bf(hc[3]) << 16);
        pk.z = (unsigned)f2bf(hc[4]) | ((unsigned)f2bf(hc[5]) << 16);
        pk.w = (unsigned)f2bf(hc[6]) | ((unsigned)f2bf(hc[7]) << 16);
        *(uint4*)&As[ty][tx * 8] = pk;
    }
    __syncthreads();

    // Phase 2: MFMA conv. wave -> row-tile rt (0..1), col-tile pair (0..2).
    int wave = tid >> 6, lane = tid & 63;
    int quad = lane >> 4, l16 = lane & 15;
    int rt = wave & 1;
    int ct0 = (wave >> 1) * 2, ct1 = ct0 + 1;

    f32x4 g0 = (f32x4){0.f,0.f,0.f,0.f}, g1 = (f32x4){0.f,0.f,0.f,0.f};
#pragma unroll
    for (int ks = 0; ks < 3; ks++) {
        short8 afrag = *(const short8*)&As[rt * 16 + l16][ks * 32 + quad * 8];
        short8 b0 = *(const short8*)&Wc[(size_t)(ct0 * 16 + l16) * HID + ks * 32 + quad * 8];
        short8 b1 = *(const short8*)&Wc[(size_t)(ct1 * 16 + l16) * HID + ks * 32 + quad * 8];
        g0 = __builtin_amdgcn_mfma_f32_16x16x32_bf16(afrag, b0, g0, 0, 0, 0);
        g1 = __builtin_amdgcn_mfma_f32_16x16x32_bf16(afrag, b1, g1, 0, 0, 0);
    }
    float ob = 1.0f - beta;
#pragma unroll
    for (int r = 0; r < 4; r++) {
        int lrow = rt * 16 + quad * 4 + r;
        int nd = snode[lrow];
        if (nd >= 0) {
            int c0 = ct0 * 16 + l16;
            int c1 = ct1 * 16 + l16;
            float v0 = ob * bf2f(As[lrow][c0]) + beta * g0[r];
            float v1 = ob * bf2f(As[lrow][c1]) + beta * g1[r];
            v0 = v0 > 0.f ? v0 : 0.f;
            v1 = v1 > 0.f ? v1 : 0.f;
            h_out[(size_t)nd * HID + c0] = (short)f2bf(v0);
            h_out[(size_t)nd * HID + c1] = (short)f2bf(v1);
        }
    }
}

// ---------------- output GEMM (MFMA bf16) + fused log_softmax ----------------
__global__ __launch_bounds__(256) void out_kernel(
        const short* __restrict__ h_bf, const short* __restrict__ Wt,
        const float* __restrict__ b, float* __restrict__ out) {
    int tid = threadIdx.x;
    int wave = tid >> 6, lane = tid & 63;
    int quad = lane >> 4, l16 = lane & 15;
    int row0 = blockIdx.x * 64 + wave * 16;

    f32x4 acc[4];
#pragma unroll
    for (int n = 0; n < 4; n++) acc[n] = (f32x4){0.f, 0.f, 0.f, 0.f};

    int arow = row0 + l16; if (arow > N_NODES) arow = N_NODES;  // dummy row is zero
#pragma unroll
    for (int ks = 0; ks < 3; ks++) {
        short8 afrag = *(const short8*)&h_bf[(size_t)arow * HID + ks * 32 + quad * 8];
#pragma unroll
        for (int n = 0; n < 4; n++) {
            short8 bfrag = *(const short8*)&Wt[(size_t)(n * 16 + l16) * HID + ks * 32 + quad * 8];
            acc[n] = __builtin_amdgcn_mfma_f32_16x16x32_bf16(afrag, bfrag, acc[n], 0, 0, 0);
        }
    }
#pragma unroll
    for (int n = 0; n < 4; n++) {
        float bias = b[n * 16 + l16];
#pragma unroll
        for (int r = 0; r < 4; r++) acc[n][r] += bias;
    }
#pragma unroll
    for (int r = 0; r < 4; r++) {
        float m = acc[0][r];
        m = fmaxf(m, acc[1][r]); m = fmaxf(m, acc[2][r]); m = fmaxf(m, acc[3][r]);
#pragma unroll
        for (int off = 1; off < 16; off <<= 1) m = fmaxf(m, __shfl_xor(m, off));
        float s = __expf(acc[0][r] - m) + __expf(acc[1][r] - m)
                + __expf(acc[2][r] - m) + __expf(acc[3][r] - m);
#pragma unroll
        for (int off = 1; off < 16; off <<= 1) s += __shfl_xor(s, off);
        float lse = m + __logf(s);
        int grow = row0 + quad * 4 + r;
        if (grow < N_NODES) {
#pragma unroll
            for (int n = 0; n < 4; n++)
                out[(size_t)grow * NCLASS + n * 16 + l16] = acc[n][r] - lse;
        }
    }
}

extern "C" void kernel_launch(void* const* d_in, const int* in_sizes, int n_in,
                              void* d_out, int out_size, void* d_ws, size_t ws_size,
                              hipStream_t stream) {
    const float* x      = (const float*)d_in[0];
    const int*   ei     = (const int*)d_in[1];
    const int*   srcp   = ei;
    const int*   dstp   = ei + N_EDGES;
    const float* W_in   = (const float*)d_in[2];
    const float* b_in   = (const float*)d_in[3];
    const float* conv_W = (const float*)d_in[4];
    const float* W_out  = (const float*)d_in[5];
    const float* b_out  = (const float*)d_in[6];
    float* out = (float*)d_out;

    short* h0  = (short*)d_ws;                               // (N+1) x HID bf16 == x0
    short* h_b = h0  + (size_t)(N_NODES + 1) * HID;
    short* h_c = h_b + (size_t)(N_NODES + 1) * HID;
    short* Wt_in  = h_c + (size_t)(N_NODES + 1) * HID;       // 96 x 512
    short* Wt_out = Wt_in + (size_t)HID * NFEAT;             // 64 x 96
    short* Wc     = Wt_out + (size_t)NCLASS * HID;           // 8 x 96 x 96 bf16
    int* deg        = (int*)(Wc + (size_t)NUM_LAYERS * HID * HID);
    int* row_start  = deg + N_NODES;
    int* cursor     = row_start + N_NODES;
    int* blk_sum    = cursor + N_NODES;
    int* blk_off    = blk_sum + 64;
    int* bin_base   = blk_off + 64;
    int* node_rank  = bin_base + 64;
    int* perm       = node_rank + N_NODES;
    int* blk_bin_cnt= perm + N_NODES;                        // NBB*64
    int* blk_bin_off= blk_bin_cnt + NBB * 64;                // NBB*64
    int* csr_src    = blk_bin_off + NBB * 64;                // <= N_EDGES + 3*N_NODES ints

    hipMemsetAsync(deg,    0, N_NODES * sizeof(int), stream);
    hipMemsetAsync(cursor, 0, N_NODES * sizeof(int), stream);
    hist_kernel<<<(N_EDGES + 255) / 256, 256, 0, stream>>>(dstp, deg);
    scan1_kernel<<<NSB, 1024, 0, stream>>>(deg, row_start, blk_sum);
    scan2_kernel<<<1, 64, 0, stream>>>(blk_sum, blk_off);
    scan3_kernel<<<NSB, 1024, 0, stream>>>(row_start, blk_off);
    fill_kernel<<<(N_EDGES + 255) / 256, 256, 0, stream>>>(srcp, dstp, row_start, cursor, csr_src);
    pad_kernel<<<(N_NODES + 255) / 256, 256, 0, stream>>>(deg, row_start, csr_src);
    bin_hist2_kernel<<<NBB, 256, 0, stream>>>(deg, node_rank, blk_bin_cnt);
    bin_offsets_kernel<<<1, 64, 0, stream>>>(blk_bin_cnt, blk_bin_off, bin_base);
    bin_place_kernel<<<NBB, 256, 0, stream>>>(deg, node_rank, blk_bin_off, bin_base, perm);

    convert_win_kernel<<<HID, NFEAT, 0, stream>>>(W_in, Wt_in);
    convert_wout_kernel<<<NCLASS, HID, 0, stream>>>(W_out, Wt_out);
    convert_wconv_kernel<<<dim3(HID, NUM_LAYERS), HID, 0, stream>>>(conv_W, Wc);
    gemm_in_kernel<<<(N_NODES + 63) / 64, 256, 0, stream>>>(x, Wt_in, b_in, h0);
    zero_dummy_kernel<<<1, 128, 0, stream>>>(h0, h_b, h_c);

    short* cur = h0;
    short* nxt = h_b;
    for (int l = 0; l < NUM_LAYERS; l++) {
        float beta = logf(0.5f / (float)(l + 1) + 1.0f);
        layer_kernel<<<(N_NODES + 31) / 32, 384, 0, stream>>>(
            cur, h0, row_start, deg, csr_src, perm, Wc + (size_t)l * HID * HID, beta, nxt);
        cur = nxt;
        nxt = (cur == h_b) ? h_c : h_b;
    }

    out_kernel<<<(N_NODES + 63) / 64, 256, 0, stream>>>(cur, Wt_out, b_out, out);
}